// Round 1
// 333.666 us; speedup vs baseline: 1.2242x; 1.2242x over previous
//
#include <hip/hip_runtime.h>
#include <cstdint>

// LeNet-5 forward, B=16384. Batch-lane design: lane = sample, wave-uniform
// control, [feature][N] layouts. R7: v_dot2_f32_f16 everywhere (2 MACs/inst,
// no f16->f32 unpack), prepacked f16 weight pairs (k_wpack -> tail of d_out),
// S2P re-paired to adjacent columns in [fh][N][2] cells (dwordx2 loads in
// c3s4), S4 as padded x-pairs (c5 = 240 loads + 2400 dot2).
// Plans/offsets identical to R6 except S4 region grows (still fits):
//   Plan A (ws >= 55,312,384): S2P u32x2[294][16384] @0 (38,535,168);
//     XP @38,535,168 (16,777,216, front); S4P u32[240][16384] @38,535,168
//     (15,728,640, after front, end 54,263,808); H5P @0 (3,932,160);
//     H6P @4,194,304 (2,752,512). 9 dispatches.
//   Plan B: XP @0 (16,777,216); S2P @16,777,216 (19,267,584);
//     S4P @0 (7,864,320); H5P @7,864,320 (1,966,080); H6P @9,830,400
//     (1,376,256). peak 36,044,800. 13 dispatches.
// Weight pack lives at d_out tail (141,504 B): only k_rbf writes d_out and
// k_rbf never reads the pack; every byte of out is rewritten by k_rbf.

typedef unsigned int u32;

union U32H2 { u32 u; _Float16 h[2]; };
__device__ __forceinline__ float f16lo(u32 v) { U32H2 a; a.u = v; return (float)a.h[0]; }
__device__ __forceinline__ float f16hi(u32 v) { U32H2 a; a.u = v; return (float)a.h[1]; }
__device__ __forceinline__ u32 packh2(float a, float b) {
    U32H2 x; x.h[0] = (_Float16)a; x.h[1] = (_Float16)b; return x.u;
}

typedef _Float16 h2v __attribute__((ext_vector_type(2)));
union U32V2 { u32 u; h2v v; };

#if defined(__has_builtin)
#if __has_builtin(__builtin_amdgcn_fdot2)
#define HAVE_FDOT2 1
#endif
#endif

// c += a.h0*b.h0 + a.h1*b.h1  (f16 mul, f32 accumulate) -> v_dot2_f32_f16
__device__ __forceinline__ float dot2(u32 a, u32 b, float c) {
    U32V2 x, y; x.u = a; y.u = b;
#ifdef HAVE_FDOT2
    return __builtin_amdgcn_fdot2(x.v, y.v, c, false);
#else
    return c + (float)x.v[0] * (float)y.v[0] + (float)x.v[1] * (float)y.v[1];
#endif
}

// pair starting at odd position: (hi(lo_pair), lo(hi_pair)) -> v_alignbit_b32
__device__ __forceinline__ u32 shf16(u32 lo, u32 hi) {
    return (lo >> 16) | (hi << 16);
}

// A*tanh(S*v), S=2/3: tanh(y) = 1 - 2/(exp(2y)+1), 2y = (4/3)v
__device__ __forceinline__ float tact(float v) {
    float e = __expf(1.3333333333f * v);
    return 1.7159f * (1.0f - 2.0f * __builtin_amdgcn_rcpf(e + 1.0f));
}

// C3 sparse connection lists (from reference CONNECTIONS)
__device__ const int C3_NIC[16] = {3,3,3,3,3,3, 4,4,4,4,4,4,4,4,4, 6};
__device__ const int C3_ICL[96] = {
    0,1,2,0,0,0,  1,2,3,0,0,0,  2,3,4,0,0,0,  3,4,5,0,0,0,
    0,4,5,0,0,0,  0,1,5,0,0,0,  0,1,2,3,0,0,  1,2,3,4,0,0,
    2,3,4,5,0,0,  0,3,4,5,0,0,  0,1,4,5,0,0,  0,1,2,5,0,0,
    0,1,3,4,0,0,  1,2,4,5,0,0,  0,2,3,5,0,0,  0,1,2,3,4,5 };

// Weight-pack layout (u32 indices inside WPK):
//  W1P @0     : [6ch][5ky][3q]   pair = (w[2q], w[2q+1]|0)         (90, pad 96)
//  W3P @96    : [96 plane][5][3] same                              (1440)
//  W5P @1536  : [120c][80g][3q]  pair = (w5[c][g*5+2q], +1|0)      (28800)
//  F6P @30336 : [84o][60i]       pair = (f6w[o][2i], f6w[o][2i+1]) (5040)
#define WPK_W1 0
#define WPK_W3 96
#define WPK_W5 1536
#define WPK_F6 30336
#define WPK_N  35376

__global__ __launch_bounds__(256) void k_wpack(
    const float* __restrict__ w1, const float* __restrict__ w3,
    const float* __restrict__ w5, const float* __restrict__ f6w,
    u32* __restrict__ wpk)
{
    const int idx = blockIdx.x * 256 + threadIdx.x;
    if (idx >= WPK_N) return;
    float a = 0.0f, b = 0.0f;
    if (idx < 96) {
        if (idx < 90) {
            int ch = idx / 15, r = idx % 15, ky = r / 3, q = r % 3;
            a = w1[ch * 25 + ky * 5 + 2 * q];
            if (q < 2) b = w1[ch * 25 + ky * 5 + 2 * q + 1];
        }
    } else if (idx < WPK_W5) {
        int t = idx - WPK_W3;
        int p = t / 15, r = t % 15, ky = r / 3, q = r % 3;
        a = w3[p * 25 + ky * 5 + 2 * q];
        if (q < 2) b = w3[p * 25 + ky * 5 + 2 * q + 1];
    } else if (idx < WPK_F6) {
        int t = idx - WPK_W5;
        int c = t / 240, r = t % 240, g = r / 3, q = r % 3;
        a = w5[c * 400 + g * 5 + 2 * q];
        if (q < 2) b = w5[c * 400 + g * 5 + 2 * q + 1];
    } else {
        int t = idx - WPK_F6;
        int o = t / 60, i = t % 60;
        a = f6w[o * 120 + 2 * i];
        b = f6w[o * 120 + 2 * i + 1];
    }
    wpk[idx] = packh2(a, b);
}

// ---------------- transpose: x chunk (8192,1024) f32 -> xp u32[512][8192] ---
// xp[r*16+j][sl] = (x[r][2j], x[r][2j+1]) f16 pair. grid (128, 16).
__global__ __launch_bounds__(256) void k_tr(const float* __restrict__ x,
                                            u32* __restrict__ xp)
{
    __shared__ _Float16 lds[64 * 66];
    const int t = threadIdx.x;
    const int tb = blockIdx.x * 64;          // sample tile
    const int tp = blockIdx.y * 64;          // position tile
    #pragma unroll
    for (int i = 0; i < 16; ++i) {           // coalesced read along positions
        int idx = i * 256 + t;
        int bl = idx >> 6, pl = idx & 63;
        lds[pl * 66 + bl] = (_Float16)x[(size_t)(tb + bl) * 1024 + tp + pl];
    }
    __syncthreads();
    #pragma unroll
    for (int j = 0; j < 8; ++j) {            // coalesced pair-write along batch
        int idx = j * 256 + t;
        int pp = idx >> 6, bl = idx & 63;    // pp in [0,32)
        U32H2 u;
        u.h[0] = lds[(2 * pp) * 66 + bl];
        u.h[1] = lds[(2 * pp + 1) * 66 + bl];
        xp[(size_t)(blockIdx.y * 32 + pp) * 8192 + tb + bl] = u.u;
    }
}

// ---------------- C1 + S2 fused, grid (32, 42) ------------------------------
// blockIdx.y = oy2*3 + chpair. New S2P layout: adjacent-column pairs in
// [fh][N][2] u32 cells: feature f = ch*98 + row*7 + p holds s2 columns
// (2p, 2p+1) of s2 row `row` (row cols 0..6 from conv row 2*row pooling,
// 7..13 from conv row 2*row+1, per pool_affine reshape semantics).
__global__ __launch_bounds__(256) void k_c1s2(
    const u32* __restrict__ xp, const u32* __restrict__ wpk,
    const float* __restrict__ b1,
    const float* __restrict__ s2w, const float* __restrict__ s2b,
    u32* __restrict__ s2p, int ostr)
{
    const int sl = blockIdx.x * 256 + threadIdx.x;
    const int oy2 = blockIdx.y / 3;
    const int cp  = blockIdx.y % 3;          // channels 2cp, 2cp+1
    const int y0 = 2 * oy2;
    const u32* xb = xp + sl;

    u32 wl[2][15];                           // f16 weight pairs (uniform)
    #pragma unroll
    for (int a = 0; a < 2; ++a)
        #pragma unroll
        for (int i = 0; i < 15; ++i) wl[a][i] = wpk[WPK_W1 + (2 * cp + a) * 15 + i];

    u32 cur[6][4];                           // aligned pairs, window cols 4qx..4qx+7
    #pragma unroll
    for (int r = 0; r < 6; ++r)
        #pragma unroll
        for (int c = 0; c < 4; ++c)
            cur[r][c] = xb[(size_t)((y0 + r) * 16 + c) * 8192];

    float va[2][7], vb[2][7];                // s2 row cols 0..6 / 7..13 per ch

    #pragma unroll
    for (int qx = 0; qx < 7; ++qx) {
        float o[2][2][4];
        #pragma unroll
        for (int a = 0; a < 2; ++a) {
            const float bbv = b1[2 * cp + a];
            #pragma unroll
            for (int u = 0; u < 2; ++u)
                #pragma unroll
                for (int d = 0; d < 4; ++d) o[a][u][d] = bbv;
        }
        #pragma unroll
        for (int r = 0; r < 6; ++r) {
            const u32 s0 = shf16(cur[r][0], cur[r][1]);
            const u32 s1 = shf16(cur[r][1], cur[r][2]);
            const u32 s2 = shf16(cur[r][2], cur[r][3]);
            const u32 s3 = cur[r][3] >> 16;  // (col7, pad0)
            #pragma unroll
            for (int u = 0; u < 2; ++u) {
                const int ky = r - u;
                if (ky < 0 || ky > 4) continue;
                #pragma unroll
                for (int a = 0; a < 2; ++a) {
                    const u32 w0 = wl[a][ky * 3 + 0];
                    const u32 w1 = wl[a][ky * 3 + 1];
                    const u32 w2 = wl[a][ky * 3 + 2];
                    o[a][u][0] = dot2(cur[r][0], w0, dot2(cur[r][1], w1, dot2(cur[r][2], w2, o[a][u][0])));
                    o[a][u][1] = dot2(s0,        w0, dot2(s1,        w1, dot2(s2,        w2, o[a][u][1])));
                    o[a][u][2] = dot2(cur[r][1], w0, dot2(cur[r][2], w1, dot2(cur[r][3], w2, o[a][u][2])));
                    o[a][u][3] = dot2(s1,        w0, dot2(s2,        w1, dot2(s3,        w2, o[a][u][3])));
                }
            }
        }
        #pragma unroll
        for (int a = 0; a < 2; ++a) {
            const int ch = 2 * cp + a;
            const float sw = s2w[ch], sb = s2b[ch];
            float m0 = 0.25f * (tact(o[a][0][0]) + tact(o[a][0][1]) + tact(o[a][0][2]) + tact(o[a][0][3]));
            float m1 = 0.25f * (tact(o[a][1][0]) + tact(o[a][1][1]) + tact(o[a][1][2]) + tact(o[a][1][3]));
            va[a][qx] = tact(sw * m0 + sb);
            vb[a][qx] = tact(sw * m1 + sb);
        }
        if (qx < 6) {                        // slide window: +2 new pairs/row
            #pragma unroll
            for (int r = 0; r < 6; ++r) {
                cur[r][0] = cur[r][2];
                cur[r][1] = cur[r][3];
                cur[r][2] = xb[(size_t)((y0 + r) * 16 + 2 * qx + 4) * 8192];
                cur[r][3] = xb[(size_t)((y0 + r) * 16 + 2 * qx + 5) * 8192];
            }
        }
    }
    // repack to adjacent-column pairs and store into [fh][ostr][2] cells
    #pragma unroll
    for (int a = 0; a < 2; ++a) {
        u32 o7[7];
        o7[0] = packh2(va[a][0], va[a][1]);
        o7[1] = packh2(va[a][2], va[a][3]);
        o7[2] = packh2(va[a][4], va[a][5]);
        o7[3] = packh2(va[a][6], vb[a][0]);
        o7[4] = packh2(vb[a][1], vb[a][2]);
        o7[5] = packh2(vb[a][3], vb[a][4]);
        o7[6] = packh2(vb[a][5], vb[a][6]);
        const int ch = 2 * cp + a;
        const int f0 = ch * 98 + oy2 * 7;    // parity = oy2&1 (uniform)
        const int fh0 = f0 >> 1;
        uint2* p2 = (uint2*)s2p;
        uint2 t;
        if ((oy2 & 1) == 0) {
            t.x = o7[0]; t.y = o7[1]; p2[(size_t)(fh0 + 0) * ostr + sl] = t;
            t.x = o7[2]; t.y = o7[3]; p2[(size_t)(fh0 + 1) * ostr + sl] = t;
            t.x = o7[4]; t.y = o7[5]; p2[(size_t)(fh0 + 2) * ostr + sl] = t;
            s2p[((size_t)(fh0 + 3) * ostr + sl) * 2] = o7[6];
        } else {
            s2p[((size_t)fh0 * ostr + sl) * 2 + 1] = o7[0];
            t.x = o7[1]; t.y = o7[2]; p2[(size_t)(fh0 + 1) * ostr + sl] = t;
            t.x = o7[3]; t.y = o7[4]; p2[(size_t)(fh0 + 2) * ostr + sl] = t;
            t.x = o7[5]; t.y = o7[6]; p2[(size_t)(fh0 + 3) * ostr + sl] = t;
        }
    }
}

// ---------------- C3 + S4 fused, grid (nb/256, 80) --------------------------
// blockIdx.y = oc*5 + y2. Window = 21 dwordx2 cells (42 adjacent-col pairs,
// rows 2y2..2y2+5). dot2 kernel taps: (kx0,kx1)(kx2,kx3)(kx4,0).
// S4 output: padded x-pairs s4p[(oc*5+y2)*3+q][nb] = (s4[2q], s4[2q+1]|0).
__global__ __launch_bounds__(256) void k_c3s4(
    const u32* __restrict__ s2p, const u32* __restrict__ wpk,
    const float* __restrict__ b3, const float* __restrict__ s4w,
    const float* __restrict__ s4b, u32* __restrict__ s4p, int nb)
{
    const int sl = blockIdx.x * 256 + threadIdx.x;
    const int oc = blockIdx.y / 5;
    const int y2 = blockIdx.y % 5;
    const int nic = C3_NIC[oc];
    const float bbv = b3[oc];

    float a2[2][10];
    #pragma unroll
    for (int u = 0; u < 2; ++u)
        #pragma unroll
        for (int ox = 0; ox < 10; ++ox) a2[u][ox] = bbv;

    for (int e = 0; e < nic; ++e) {          // uniform sparse plane loop
        const int ic = C3_ICL[oc * 6 + e];
        const uint2* sp2 = (const uint2*)s2p + (size_t)(ic * 49 + y2 * 7) * nb + sl;
        u32 wa[6][7];                        // aligned pairs, rows 2y2..2y2+5
        #pragma unroll
        for (int k = 0; k < 21; ++k) {
            const uint2 v = sp2[(size_t)k * nb];
            wa[(2 * k) / 7][(2 * k) % 7]         = v.x;
            wa[(2 * k + 1) / 7][(2 * k + 1) % 7] = v.y;
        }
        u32 wl[15];                          // uniform f16 weight pairs
        #pragma unroll
        for (int i = 0; i < 15; ++i) wl[i] = wpk[WPK_W3 + (oc * 6 + ic) * 15 + i];
        #pragma unroll
        for (int r = 0; r < 6; ++r) {
            u32 sh[7];                       // odd-start pairs for this row
            #pragma unroll
            for (int j = 0; j < 6; ++j) sh[j] = shf16(wa[r][j], wa[r][j + 1]);
            sh[6] = wa[r][6] >> 16;          // (col13, pad0)
            #pragma unroll
            for (int u = 0; u < 2; ++u) {
                const int ky = r - u;
                if (ky < 0 || ky > 4) continue;
                const u32 w0 = wl[ky * 3 + 0];
                const u32 w1 = wl[ky * 3 + 1];
                const u32 w2 = wl[ky * 3 + 2];
                #pragma unroll
                for (int ox = 0; ox < 10; ox += 2) {
                    const int p = ox >> 1;
                    a2[u][ox]     = dot2(wa[r][p], w0, dot2(wa[r][p + 1], w1, dot2(wa[r][p + 2], w2, a2[u][ox])));
                    a2[u][ox + 1] = dot2(sh[p],    w0, dot2(sh[p + 1],    w1, dot2(sh[p + 2],    w2, a2[u][ox + 1])));
                }
            }
        }
    }
    // tanh, then S4 reshape-flat pooling over local flat f = u*10+ox
    float tv[20];
    #pragma unroll
    for (int u = 0; u < 2; ++u)
        #pragma unroll
        for (int ox = 0; ox < 10; ++ox) tv[u * 10 + ox] = tact(a2[u][ox]);
    const float swv = s4w[oc], sbv = s4b[oc];
    float so[5];
    #pragma unroll
    for (int x2 = 0; x2 < 5; ++x2)
        so[x2] = tact(0.25f * (tv[x2 * 4] + tv[x2 * 4 + 1] + tv[x2 * 4 + 2] + tv[x2 * 4 + 3]) * swv + sbv);
    const size_t g = (size_t)(oc * 5 + y2) * 3;
    s4p[(g + 0) * nb + sl] = packh2(so[0], so[1]);
    s4p[(g + 1) * nb + sl] = packh2(so[2], so[3]);
    s4p[(g + 2) * nb + sl] = packh2(so[4], 0.0f);
}

// ---------------- C5: 120-ch GEMV over 240 s4 pairs, grid (nb/256, 12) ------
__global__ __launch_bounds__(256) void k_c5(
    const u32* __restrict__ s4p, const u32* __restrict__ wpk,
    const float* __restrict__ b5, u32* __restrict__ h5p, int nb)
{
    const int sl = blockIdx.x * 256 + threadIdx.x;
    const int chg = blockIdx.y;              // channels chg*10 .. chg*10+9
    const u32* wp = wpk + WPK_W5 + chg * 10 * 240;
    float acc[10];
    #pragma unroll
    for (int c = 0; c < 10; ++c) acc[c] = b5[chg * 10 + c];
    #pragma unroll 4
    for (int i = 0; i < 240; ++i) {
        const u32 v = s4p[(size_t)i * nb + sl];
        #pragma unroll
        for (int c = 0; c < 10; ++c)
            acc[c] = dot2(v, wp[c * 240 + i], acc[c]);   // uniform -> s_load
    }
    #pragma unroll
    for (int j = 0; j < 5; ++j)
        h5p[(size_t)(chg * 5 + j) * nb + sl] =
            packh2(tact(acc[2 * j]), tact(acc[2 * j + 1]));
}

// ---------------- F6: 84-out GEMV over 60 h5 pairs, grid (nb/256, 6) --------
__global__ __launch_bounds__(256) void k_f6(
    const u32* __restrict__ h5p, const u32* __restrict__ wpk,
    const float* __restrict__ f6b, u32* __restrict__ h6p, int nb)
{
    const int sl = blockIdx.x * 256 + threadIdx.x;
    const int og = blockIdx.y;               // outputs og*14 .. og*14+13
    const u32* wp = wpk + WPK_F6 + og * 14 * 60;
    float acc[14];
    #pragma unroll
    for (int o = 0; o < 14; ++o) acc[o] = f6b[og * 14 + o];
    #pragma unroll 4
    for (int i = 0; i < 60; ++i) {
        const u32 v = h5p[(size_t)i * nb + sl];
        #pragma unroll
        for (int o = 0; o < 14; ++o)
            acc[o] = dot2(v, wp[o * 60 + i], acc[o]);    // uniform -> s_load
    }
    #pragma unroll
    for (int j = 0; j < 7; ++j)
        h6p[(size_t)(og * 7 + j) * nb + sl] =
            packh2(tact(acc[2 * j]), tact(acc[2 * j + 1]));
}

// ---------------- RBF head, grid (nb/256, 5): 2 classes per block -----------
__global__ __launch_bounds__(256) void k_rbf(
    const u32* __restrict__ h6p, const float* __restrict__ rbf,
    float* __restrict__ out, int nb)
{
    const int sl = blockIdx.x * 256 + threadIdx.x;
    const int gy = blockIdx.y;
    float hv[84];
    #pragma unroll
    for (int i = 0; i < 42; ++i) {
        const u32 v = h6p[(size_t)i * nb + sl];
        hv[2 * i]     = f16lo(v);
        hv[2 * i + 1] = f16hi(v);
    }
    #pragma unroll
    for (int a = 0; a < 2; ++a) {
        const int c = 2 * gy + a;
        float acc = 0.0f;
        #pragma unroll 4
        for (int i = 0; i < 84; ++i) {
            float d = hv[i] - rbf[c * 84 + i];   // uniform -> s_load
            acc += d * d;
        }
        out[(size_t)sl * 10 + c] = acc;
    }
}

extern "C" void kernel_launch(void* const* d_in, const int* in_sizes, int n_in,
                              void* d_out, int out_size, void* d_ws, size_t ws_size,
                              hipStream_t stream)
{
    const float* x    = (const float*)d_in[0];
    const float* w1   = (const float*)d_in[1];
    const float* b1   = (const float*)d_in[2];
    const float* s2w  = (const float*)d_in[3];
    const float* s2b  = (const float*)d_in[4];
    const float* w3   = (const float*)d_in[5];
    const float* b3   = (const float*)d_in[6];
    const float* s4w  = (const float*)d_in[7];
    const float* s4b  = (const float*)d_in[8];
    const float* w5   = (const float*)d_in[9];
    const float* b5   = (const float*)d_in[10];
    const float* f6w  = (const float*)d_in[11];
    const float* f6b  = (const float*)d_in[12];
    const float* rbfw = (const float*)d_in[13];
    float* out = (float*)d_out;
    char* ws = (char*)d_ws;

    // Weight pack at the tail of d_out (dead until k_rbf; k_rbf never reads
    // it and rewrites every byte of out at the end of each plan/chunk order).
    u32* WPK = (u32*)((char*)d_out +
                      (((size_t)out_size - (size_t)(WPK_N * 4)) & ~(size_t)7));
    k_wpack<<<dim3((WPK_N + 255) / 256), 256, 0, stream>>>(w1, w3, w5, f6w, WPK);

    if (ws_size >= 55312384) {
        // ---- Plan A: full-batch tail (9 dispatches) ----
        u32* S2P = (u32*)(ws);                       // 38,535,168 B (cells)
        u32* XP  = (u32*)(ws + 38535168);            // 16,777,216 B (front)
        u32* S4P = (u32*)(ws + 38535168);            // 15,728,640 B (after front)
        u32* H5P = (u32*)(ws);                       //  3,932,160 B (after c3s4)
        u32* H6P = (u32*)(ws + 4194304);             //  2,752,512 B
        for (int c = 0; c < 2; ++c) {
            k_tr  <<<dim3(128, 16), 256, 0, stream>>>(x + (size_t)c * 8192 * 1024, XP);
            k_c1s2<<<dim3(32, 42), 256, 0, stream>>>(XP, WPK, b1, s2w, s2b,
                                                     S2P + (size_t)c * 16384, 16384);
        }
        k_c3s4<<<dim3(64, 80), 256, 0, stream>>>(S2P, WPK, b3, s4w, s4b, S4P, 16384);
        k_c5  <<<dim3(64, 12), 256, 0, stream>>>(S4P, WPK, b5, H5P, 16384);
        k_f6  <<<dim3(64, 6), 256, 0, stream>>>(H5P, WPK, f6b, H6P, 16384);
        k_rbf <<<dim3(64, 5), 256, 0, stream>>>(H6P, rbfw, out, 16384);
    } else {
        // ---- Plan B: 2 chunks (13 dispatches) ----
        u32* XP  = (u32*)(ws);                       // 16,777,216 B
        u32* S2P = (u32*)(ws + 16777216);            // 19,267,584 B
        u32* S4P = (u32*)(ws);                       //  7,864,320 B (XP dead)
        u32* H5P = (u32*)(ws + 7864320);             //  1,966,080 B
        u32* H6P = (u32*)(ws + 9830400);             //  1,376,256 B
        for (int c = 0; c < 2; ++c) {
            k_tr  <<<dim3(128, 16), 256, 0, stream>>>(x + (size_t)c * 8192 * 1024, XP);
            k_c1s2<<<dim3(32, 42), 256, 0, stream>>>(XP, WPK, b1, s2w, s2b, S2P, 8192);
            k_c3s4<<<dim3(32, 80), 256, 0, stream>>>(S2P, WPK, b3, s4w, s4b, S4P, 8192);
            k_c5  <<<dim3(32, 12), 256, 0, stream>>>(S4P, WPK, b5, H5P, 8192);
            k_f6  <<<dim3(32, 6), 256, 0, stream>>>(H5P, WPK, f6b, H6P, 8192);
            k_rbf <<<dim3(32, 5), 256, 0, stream>>>(H6P, rbfw, out + (size_t)c * 8192 * 10, 8192);
        }
    }
}